// Round 4
// baseline (420.783 us; speedup 1.0000x reference)
//
#include <hip/hip_runtime.h>
#include <hip/hip_bf16.h>
#include <cstdint>

#define B_DIM 8192
#define N_DIM 64
#define C_DIM 16
#define D_DIM 1024
#define NUM 32
#define NCAUSAL 16
#define K_RANGES 8
#define HS 1024
#define HP 1024
#define TAU 0.7f
#define SMOOTH 0.1f

typedef __bf16 bf16x8 __attribute__((ext_vector_type(8)));
typedef float f32x16 __attribute__((ext_vector_type(16)));

typedef const __attribute__((address_space(1))) uint32_t* gas_ptr;
typedef __attribute__((address_space(3))) uint32_t* las_ptr;

__device__ __forceinline__ void gld_lds16(const void* g, void* l) {
    __builtin_amdgcn_global_load_lds((gas_ptr)(uintptr_t)g,
                                     (las_ptr)(uint32_t)(uintptr_t)l,
                                     16, 0, 0);
}

__device__ __forceinline__ int swz(int r) { return (r & 3) ^ ((r >> 2) & 3); }

// ---------------------------------------------------------------------------
// GEMM body: C[256 x 128 tile] = act(A[M x K, ld=lda] * Bt[Npad x K]^T + bias)
// 4 waves, wave-tile 128x64 (4x2 of 32x32x16 MFMA).
// A: direct global->VGPR per-lane dwordx4 (L1-served, line-aligned reuse).
// B: LDS double-buffered via global_load_lds, xor-swizzled, staged 1 iter ahead.
// ACT: 0 = none (f32 out), 1 = relu (bf16 out), 2 = sigmoid (f32 out)
// ---------------------------------------------------------------------------
template <int ACT>
__device__ __forceinline__ void gemm_body(
    const ushort* __restrict__ Ag, const ushort* __restrict__ Bg,
    const float* __restrict__ bias,
    float* __restrict__ Cf, __hip_bfloat16* __restrict__ Cb,
    int lda, int Nout, int ldC, int K, long m0, long n0,
    uint4 (*Bs)[512])
{
    const int tid  = threadIdx.x;
    const int wave = tid >> 6;
    const int lane = tid & 63;
    const int wr = wave >> 1, wc = wave & 1;     // 2x2 wave grid
    const int ln31 = lane & 31, blk = lane >> 5;

    f32x16 acc[4][2];
#pragma unroll
    for (int i = 0; i < 4; ++i)
#pragma unroll
        for (int j = 0; j < 2; ++j) acc[i][j] = (f32x16)(0.0f);

    // per-lane A row bases (rows fixed for whole kernel)
    const ushort* Ap[4];
#pragma unroll
    for (int mi = 0; mi < 4; ++mi)
        Ap[mi] = Ag + (m0 + wr * 128 + mi * 32 + ln31) * (long)lda + blk * 8;

    uint4 Ar[2][2][4];   // [set][ks][mi]

    // B staging: 128 cols x 4 chunks(8 bf16), xor-swizzled chunk slots, 8 KB/buf
#define STAGE_B(buf, kt)                                                       \
    {                                                                          \
        int s0 = tid;        int c0_ = s0 >> 2, h0 = (s0 & 3) ^ swz(c0_);      \
        gld_lds16(Bg + (n0 + c0_) * (long)K + (kt) + h0 * 8,                   \
                  &Bs[buf][wave << 6]);                                        \
        int s1 = 256 + tid;  int c1_ = s1 >> 2, h1 = (s1 & 3) ^ swz(c1_);      \
        gld_lds16(Bg + (n0 + c1_) * (long)K + (kt) + h1 * 8,                   \
                  &Bs[buf][256 + (wave << 6)]);                                \
    }

#define LOAD_A(set, kt)                                                        \
    {                                                                          \
        _Pragma("unroll")                                                      \
        for (int ks = 0; ks < 2; ++ks)                                         \
            _Pragma("unroll")                                                  \
            for (int mi = 0; mi < 4; ++mi)                                     \
                Ar[set][ks][mi] =                                              \
                    *(const uint4*)(Ap[mi] + (kt) + ks * 16);                  \
    }

#define COMPUTE(set, buf)                                                      \
    {                                                                          \
        bf16x8 bfr[2][2];                                                      \
        _Pragma("unroll")                                                      \
        for (int ks = 0; ks < 2; ++ks)                                         \
            _Pragma("unroll")                                                  \
            for (int ni = 0; ni < 2; ++ni) {                                   \
                int n_ = wc * 64 + ni * 32 + ln31;                             \
                bfr[ks][ni] = __builtin_bit_cast(                              \
                    bf16x8, Bs[buf][n_ * 4 + ((ks * 2 + blk) ^ swz(n_))]);     \
            }                                                                  \
        _Pragma("unroll")                                                      \
        for (int ks = 0; ks < 2; ++ks)                                         \
            _Pragma("unroll")                                                  \
            for (int mi = 0; mi < 4; ++mi)                                     \
                _Pragma("unroll")                                              \
                for (int ni = 0; ni < 2; ++ni)                                 \
                    acc[mi][ni] = __builtin_amdgcn_mfma_f32_32x32x16_bf16(     \
                        __builtin_bit_cast(bf16x8, Ar[set][ks][mi]),           \
                        bfr[ks][ni], acc[mi][ni], 0, 0, 0);                    \
    }

    STAGE_B(0, 0);
    LOAD_A(0, 0);
    for (int kt = 0; kt < K; kt += 64) {     // K is a multiple of 64
        __syncthreads();
        if (kt + 32 < K) { STAGE_B(1, kt + 32); LOAD_A(1, kt + 32); }
        COMPUTE(0, 0);
        __syncthreads();
        if (kt + 64 < K) { STAGE_B(0, kt + 64); LOAD_A(0, kt + 64); }
        COMPUTE(1, 1);
    }
#undef STAGE_B
#undef LOAD_A
#undef COMPUTE

    float bs2[2];
#pragma unroll
    for (int ni = 0; ni < 2; ++ni) {
        long col = n0 + wc * 64 + ni * 32 + ln31;
        bs2[ni] = (col < Nout && bias) ? bias[col] : 0.0f;
    }

    // C/D layout: col = lane&31, row = (reg&3) + 8*(reg>>2) + 4*(lane>>5)
#pragma unroll
    for (int mi = 0; mi < 4; ++mi) {
#pragma unroll
        for (int ni = 0; ni < 2; ++ni) {
            long col = n0 + wc * 64 + ni * 32 + ln31;
            if (col >= Nout) continue;
#pragma unroll
            for (int reg = 0; reg < 16; ++reg) {
                long row = m0 + wr * 128 + mi * 32 + (reg & 3) + 8 * (reg >> 2) + 4 * blk;
                float v = acc[mi][ni][reg] + bs2[ni];
                if (ACT == 1) {
                    v = fmaxf(v, 0.0f);
                    Cb[row * (long)ldC + col] = __float2bfloat16(v);
                } else if (ACT == 2) {
                    v = 1.0f / (1.0f + __expf(-v));
                    Cf[row * (long)ldC + col] = v;
                } else {
                    Cf[row * (long)ldC + col] = v;
                }
            }
        }
    }
}

template <int ACT>
__global__ __launch_bounds__(256, 2) void gemm_bt(
    const __hip_bfloat16* __restrict__ A, const __hip_bfloat16* __restrict__ Bt,
    const float* __restrict__ bias,
    float* __restrict__ Cf, __hip_bfloat16* __restrict__ Cb,
    int lda, int Nout, int ldC, int K)
{
    __shared__ uint4 Bs[2][512];
    gemm_body<ACT>((const ushort*)A, (const ushort*)Bt, bias, Cf, Cb,
                   lda, Nout, ldC, K,
                   (long)blockIdx.y * 256, (long)blockIdx.x * 128, Bs);
}

// Fused: blocks x<8 do p2 GEMM (relu bf16), block x==8 does sel-L2 (sigmoid f32).
__global__ __launch_bounds__(256, 2) void gemm_fused23(
    const __hip_bfloat16* __restrict__ act1,   // B x 2048 (sel | policy)
    const __hip_bfloat16* __restrict__ p2t, const float* __restrict__ pb2,
    __hip_bfloat16* __restrict__ actB,
    const __hip_bfloat16* __restrict__ w2t, const float* __restrict__ sel_b2,
    float* __restrict__ outP)
{
    __shared__ uint4 Bs[2][512];
    long m0 = (long)blockIdx.y * 256;
    if (blockIdx.x < 8) {
        gemm_body<1>((const ushort*)(act1 + 1024), (const ushort*)p2t, pb2,
                     nullptr, actB, 2048, 1024, 1024, 1024,
                     m0, (long)blockIdx.x * 128, Bs);
    } else {
        gemm_body<2>((const ushort*)act1, (const ushort*)w2t, sel_b2,
                     outP, nullptr, 2048, 64, 64, 1024,
                     m0, 0, Bs);
    }
}

// ---------------------------------------------------------------------------
// Prep: batched transpose-cast (6 weight matrices) + rmean + bias concat
// ---------------------------------------------------------------------------
struct PrepArgs {
    const float* src[6];
    __hip_bfloat16* dst[6];
    int Nsrc[6];
    int Npad[6];
    const float* ranges; float* rmean;
    const float* b1; const float* b2; float* bcat;
};

__global__ void prep_kernel(PrepArgs a)
{
    int z = blockIdx.z;
    int tx = threadIdx.x, ty = threadIdx.y;   // 32 x 8
    if (z == 6) {
        if (blockIdx.x || blockIdx.y) return;
        int t = ty * 32 + tx;
        for (int j = t; j < NUM * C_DIM; j += 256) {
            float s = 0.0f;
#pragma unroll
            for (int k = 0; k < K_RANGES; ++k) s += a.ranges[j * K_RANGES + k];
            a.rmean[j] = s * (1.0f / K_RANGES);
        }
        for (int j = t; j < 1024; j += 256) {
            a.bcat[j]        = a.b1[j];
            a.bcat[1024 + j] = a.b2[j];
        }
        return;
    }
    const int Nsrc = a.Nsrc[z], Npad = a.Npad[z];
    int n0 = blockIdx.x * 32, k0 = blockIdx.y * 32;
    if (n0 >= Npad) return;
    const float* src = a.src[z];
    __hip_bfloat16* dst = a.dst[z];
    __shared__ float tile[32][33];
#pragma unroll
    for (int i = 0; i < 32; i += 8) {
        int k = k0 + ty + i, n = n0 + tx;
        tile[ty + i][tx] = (n < Nsrc) ? src[(size_t)k * Nsrc + n] : 0.0f;
    }
    __syncthreads();
#pragma unroll
    for (int i = 0; i < 32; i += 8) {
        int n = n0 + ty + i, k = k0 + tx;
        dst[(size_t)n * D_DIM + k] = __float2bfloat16(tile[tx][ty + i]);
    }
}

__global__ void cast_bf16_kernel(const float* __restrict__ src,
                                 __hip_bfloat16* __restrict__ dst, int count4)
{
    int i = blockIdx.x * blockDim.x + threadIdx.x;
    if (i >= count4) return;
    float4 v = ((const float4*)src)[i];
    __hip_bfloat16* d = dst + (size_t)i * 4;
    d[0] = __float2bfloat16(v.x);
    d[1] = __float2bfloat16(v.y);
    d[2] = __float2bfloat16(v.z);
    d[3] = __float2bfloat16(v.w);
}

// ---------------------------------------------------------------------------
// Finalize: one thread per (b, n)
// ---------------------------------------------------------------------------
__global__ void finalize_kernel(
    const float* __restrict__ x, const float* __restrict__ truth,
    const float* __restrict__ ua, const float* __restrict__ ub,
    const float* __restrict__ gum, const float* __restrict__ rmean,
    const float* __restrict__ P, const float* __restrict__ W,
    float* __restrict__ out_truth, float* __restrict__ out_xcf)
{
    int idx = blockIdx.x * 256 + threadIdx.x;
    if (idx >= B_DIM * N_DIM) return;
    int b = idx >> 6, n = idx & 63;

    float tx = truth[idx];
    out_truth[idx] = tx;

    float p  = P[idx];
    float ea = -1.0f / logf(ua[idx]);
    float eb = -1.0f / logf(ub[idx]);
    float no = p * ea;
    float probs = no / (no + (1.0f - p) * eb);

    const float* Wrow = W + (size_t)idx * 16;
    const float* grow = gum + (size_t)idx * 16;
    float lo[16], g[16], xv[16];
#pragma unroll
    for (int c = 0; c < 16; c += 4) {
        float4 v = *(const float4*)(Wrow + c);
        lo[c] = v.x; lo[c + 1] = v.y; lo[c + 2] = v.z; lo[c + 3] = v.w;
        float4 gv = *(const float4*)(grow + c);
        g[c] = gv.x; g[c + 1] = gv.y; g[c + 2] = gv.z; g[c + 3] = gv.w;
    }

    bool needx = (n < NCAUSAL) || (n >= NUM);
    if (needx) {
        const float* xrow = x + (size_t)idx * 16;
#pragma unroll
        for (int c = 0; c < 16; c += 4) {
            float4 v = *(const float4*)(xrow + c);
            xv[c] = v.x; xv[c + 1] = v.y; xv[c + 2] = v.z; xv[c + 3] = v.w;
        }
    }

    if (n < NCAUSAL) {
        int curr = 0; float best = xv[0];
#pragma unroll
        for (int c = 1; c < 16; ++c)
            if (xv[c] > best) { best = xv[c]; curr = c; }
#pragma unroll
        for (int c = 0; c < 16; ++c) lo[c] += (c < curr) ? -100.0f : 1.0f;
    }

    float mx = lo[0];
#pragma unroll
    for (int c = 1; c < 16; ++c) mx = fmaxf(mx, lo[c]);
    float s = 0.0f, pr[16];
#pragma unroll
    for (int c = 0; c < 16; ++c) { pr[c] = __expf(lo[c] - mx); s += pr[c]; }
    float inv = 1.0f / s;
#pragma unroll
    for (int c = 0; c < 16; ++c)
        pr[c] = (1.0f - SMOOTH) * pr[c] * inv + (SMOOTH / C_DIM);

    float t[16];
    float mx2 = -1e30f;
#pragma unroll
    for (int c = 0; c < 16; ++c) {
        t[c] = (__logf(pr[c]) + g[c]) * (1.0f / TAU);
        mx2 = fmaxf(mx2, t[c]);
    }
    float s2 = 0.0f;
#pragma unroll
    for (int c = 0; c < 16; ++c) { t[c] = __expf(t[c] - mx2); s2 += t[c]; }
    float inv2 = 1.0f / s2;

    if (n < NUM) {
        float xt = 0.0f;
#pragma unroll
        for (int c = 0; c < 16; ++c) xt += t[c] * inv2 * rmean[n * 16 + c];
        out_xcf[(size_t)b * 544 + n] = probs * xt + (1.0f - probs) * tx;
    } else {
        float* o = out_xcf + (size_t)b * 544 + 32 + (size_t)(n - NUM) * 16;
#pragma unroll
        for (int c = 0; c < 16; ++c)
            o[c] = probs * t[c] * inv2 + (1.0f - probs) * xv[c];
    }
}

// ---------------------------------------------------------------------------
extern "C" void kernel_launch(void* const* d_in, const int* in_sizes, int n_in,
                              void* d_out, int out_size, void* d_ws, size_t ws_size,
                              hipStream_t stream)
{
    const float* x      = (const float*)d_in[0];
    const float* truth  = (const float*)d_in[1];
    const float* sel_w1 = (const float*)d_in[2];
    const float* sel_b1 = (const float*)d_in[3];
    const float* sel_w2 = (const float*)d_in[4];
    const float* sel_b2 = (const float*)d_in[5];
    const float* pw1    = (const float*)d_in[6];
    const float* pb1    = (const float*)d_in[7];
    const float* pw2    = (const float*)d_in[8];
    const float* pb2    = (const float*)d_in[9];
    const float* pw3    = (const float*)d_in[10];
    const float* pb3    = (const float*)d_in[11];
    const float* pw4    = (const float*)d_in[12];
    const float* pb4    = (const float*)d_in[13];
    const float* ranges = (const float*)d_in[14];
    const float* ua     = (const float*)d_in[15];
    const float* ub     = (const float*)d_in[16];
    const float* gum    = (const float*)d_in[17];

    float* out       = (float*)d_out;
    float* out_truth = out;                       // B*N
    float* out_xcf   = out + 524288;              // B*544
    float* out_P     = out + 4980736;             // B*N
    float* out_W     = out + 5505024;             // B*D

    // workspace layout (16B-aligned sections)
    char* w = (char*)d_ws;
    size_t off = 0;
    __hip_bfloat16* A0   = (__hip_bfloat16*)(w + off); off += (size_t)B_DIM * D_DIM * 2;       // 16 MiB
    __hip_bfloat16* act1 = (__hip_bfloat16*)(w + off); off += (size_t)B_DIM * 2048 * 2;        // 32 MiB
    __hip_bfloat16* actB = (__hip_bfloat16*)(w + off); off += (size_t)B_DIM * HP * 2;
    __hip_bfloat16* actC = (__hip_bfloat16*)(w + off); off += (size_t)B_DIM * HP * 2;
    __hip_bfloat16* Wcat = (__hip_bfloat16*)(w + off); off += (size_t)2048 * D_DIM * 2;        // sel_w1^T | pw1^T
    __hip_bfloat16* w2t  = (__hip_bfloat16*)(w + off); off += (size_t)128 * HS * 2;            // padded 64->128
    __hip_bfloat16* p2t  = (__hip_bfloat16*)(w + off); off += (size_t)HP * HP * 2;
    __hip_bfloat16* p3t  = (__hip_bfloat16*)(w + off); off += (size_t)HP * HP * 2;
    __hip_bfloat16* p4t  = (__hip_bfloat16*)(w + off); off += (size_t)D_DIM * HP * 2;
    float* rmean         = (float*)(w + off);          off += 512 * 4;
    float* bcat          = (float*)(w + off);          off += 2048 * 4;
    if (ws_size < off) return;

    PrepArgs pa;
    pa.src[0] = sel_w1; pa.dst[0] = Wcat;               pa.Nsrc[0] = HS;   pa.Npad[0] = 1024;
    pa.src[1] = pw1;    pa.dst[1] = Wcat + 1024 * 1024; pa.Nsrc[1] = HP;   pa.Npad[1] = 1024;
    pa.src[2] = sel_w2; pa.dst[2] = w2t;                pa.Nsrc[2] = N_DIM; pa.Npad[2] = 128;
    pa.src[3] = pw2;    pa.dst[3] = p2t;                pa.Nsrc[3] = HP;   pa.Npad[3] = 1024;
    pa.src[4] = pw3;    pa.dst[4] = p3t;                pa.Nsrc[4] = HP;   pa.Npad[4] = 1024;
    pa.src[5] = pw4;    pa.dst[5] = p4t;                pa.Nsrc[5] = D_DIM; pa.Npad[5] = 1024;
    pa.ranges = ranges; pa.rmean = rmean;
    pa.b1 = sel_b1; pa.b2 = pb1; pa.bcat = bcat;

    cast_bf16_kernel<<<(B_DIM * D_DIM / 4 + 255) / 256, 256, 0, stream>>>(x, A0, B_DIM * D_DIM / 4);
    prep_kernel<<<dim3(32, 32, 7), dim3(32, 8), 0, stream>>>(pa);

    // Layer 1 fused (sel + policy): A0 x Wcat^T -> act1 (B x 2048), relu
    gemm_bt<1><<<dim3(16, 32), 256, 0, stream>>>(A0, Wcat, bcat, nullptr, act1,
                                                 D_DIM, 2048, 2048, D_DIM);
    // p2 GEMM + sel layer-2 (fused launch)
    gemm_fused23<<<dim3(9, 32), 256, 0, stream>>>(act1, p2t, pb2, actB, w2t, sel_b2, out_P);
    // p3
    gemm_bt<1><<<dim3(8, 32), 256, 0, stream>>>(actB, p3t, pb3, nullptr, actC,
                                                HP, HP, HP, HP);
    // p4 -> W
    gemm_bt<0><<<dim3(8, 32), 256, 0, stream>>>(actC, p4t, pb4, out_W, nullptr,
                                                HP, D_DIM, D_DIM, HP);

    finalize_kernel<<<(B_DIM * N_DIM + 255) / 256, 256, 0, stream>>>(
        x, truth, ua, ub, gum, rmean, out_P, out_W, out_truth, out_xcf);
}

// Round 6
// 301.922 us; speedup vs baseline: 1.3937x; 1.3937x over previous
//
#include <hip/hip_runtime.h>
#include <hip/hip_bf16.h>
#include <cstdint>

#define B_DIM 8192
#define N_DIM 64
#define C_DIM 16
#define D_DIM 1024
#define NUM 32
#define NCAUSAL 16
#define K_RANGES 8
#define HS 1024
#define HP 1024
#define TAU 0.7f
#define SMOOTH 0.1f

typedef __bf16 bf16x8 __attribute__((ext_vector_type(8)));
typedef float f32x16 __attribute__((ext_vector_type(16)));

typedef const __attribute__((address_space(1))) uint32_t* gas_ptr;
typedef __attribute__((address_space(3))) uint32_t* las_ptr;

__device__ __forceinline__ void gld_lds16(const void* g, void* l) {
    __builtin_amdgcn_global_load_lds((gas_ptr)(uintptr_t)g,
                                     (las_ptr)(uint32_t)(uintptr_t)l,
                                     16, 0, 0);
}

__device__ __forceinline__ int swz(int r) { return (r & 3) ^ ((r >> 2) & 3); }

// ---------------------------------------------------------------------------
// MI=2 GEMM body — R2-proven (passed, absmax 0.0156): 128x128 tile, 4 waves
// 2x2, wave-tile 64x64 (2x2 of 32x32x16), 4 DMA/wave, single-barrier dbuf.
// ACT: 0 = none (f32 out), 1 = relu (bf16 out), 2 = sigmoid (f32 out)
// ---------------------------------------------------------------------------
template <int ACT>
__device__ __forceinline__ void gemm_body2(
    const ushort* __restrict__ Ag, const ushort* __restrict__ Bg,
    const float* __restrict__ bias,
    float* __restrict__ Cf, __hip_bfloat16* __restrict__ Cb,
    int lda, int Nout, int ldC, int K, long m0, long n0,
    uint4 (*As)[512], uint4 (*Bs)[512])
{
    const int tid  = threadIdx.x;
    const int wave = tid >> 6;
    const int lane = tid & 63;
    const int wr = wave >> 1, wc = wave & 1;
    const int ln31 = lane & 31, blk = lane >> 5;

    f32x16 acc[2][2];
#pragma unroll
    for (int i = 0; i < 2; ++i)
#pragma unroll
        for (int j = 0; j < 2; ++j) acc[i][j] = (f32x16)(0.0f);

    const int c0 = wave * 128 + lane;
    const int c1 = wave * 128 + 64 + lane;

#define ISSUE_STAGE(buf, kt)                                                   \
    {                                                                          \
        int r0 = c0 >> 2, kc0 = (c0 & 3) ^ swz(r0);                            \
        int r1 = c1 >> 2, kc1 = (c1 & 3) ^ swz(r1);                            \
        gld_lds16(Ag + (m0 + r0) * (long)lda + (kt) + kc0 * 8,                 \
                  &As[buf][wave * 128]);                                       \
        gld_lds16(Bg + (n0 + r0) * (long)K + (kt) + kc0 * 8,                   \
                  &Bs[buf][wave * 128]);                                       \
        gld_lds16(Ag + (m0 + r1) * (long)lda + (kt) + kc1 * 8,                 \
                  &As[buf][wave * 128 + 64]);                                  \
        gld_lds16(Bg + (n0 + r1) * (long)K + (kt) + kc1 * 8,                   \
                  &Bs[buf][wave * 128 + 64]);                                  \
    }

    ISSUE_STAGE(0, 0);
    int cur = 0;
    for (int kt = 0; kt < K; kt += 32) {
        __syncthreads();
        if (kt + 32 < K) ISSUE_STAGE(cur ^ 1, kt + 32);

        bf16x8 af[2][2], bfr[2][2];
#pragma unroll
        for (int ks = 0; ks < 2; ++ks) {
            int ch = ks * 2 + blk;
#pragma unroll
            for (int mi = 0; mi < 2; ++mi) {
                int r = wr * 64 + mi * 32 + ln31;
                af[ks][mi] = __builtin_bit_cast(bf16x8, As[cur][r * 4 + (ch ^ swz(r))]);
            }
#pragma unroll
            for (int ni = 0; ni < 2; ++ni) {
                int n = wc * 64 + ni * 32 + ln31;
                bfr[ks][ni] = __builtin_bit_cast(bf16x8, Bs[cur][n * 4 + (ch ^ swz(n))]);
            }
        }
#pragma unroll
        for (int ks = 0; ks < 2; ++ks)
#pragma unroll
            for (int mi = 0; mi < 2; ++mi)
#pragma unroll
                for (int ni = 0; ni < 2; ++ni)
                    acc[mi][ni] = __builtin_amdgcn_mfma_f32_32x32x16_bf16(
                        af[ks][mi], bfr[ks][ni], acc[mi][ni], 0, 0, 0);
        cur ^= 1;
    }
#undef ISSUE_STAGE

    float bs2[2];
#pragma unroll
    for (int ni = 0; ni < 2; ++ni) {
        long col = n0 + wc * 64 + ni * 32 + ln31;
        bs2[ni] = (col < Nout && bias) ? bias[col] : 0.0f;
    }

#pragma unroll
    for (int mi = 0; mi < 2; ++mi) {
#pragma unroll
        for (int ni = 0; ni < 2; ++ni) {
            long col = n0 + wc * 64 + ni * 32 + ln31;
            if (col >= Nout) continue;
#pragma unroll
            for (int reg = 0; reg < 16; ++reg) {
                long row = m0 + wr * 64 + mi * 32 + (reg & 3) + 8 * (reg >> 2) + 4 * blk;
                float v = acc[mi][ni][reg] + bs2[ni];
                if (ACT == 1) {
                    v = fmaxf(v, 0.0f);
                    Cb[row * (long)ldC + col] = __float2bfloat16(v);
                } else if (ACT == 2) {
                    v = 1.0f / (1.0f + __expf(-v));
                    Cf[row * (long)ldC + col] = v;
                } else {
                    Cf[row * (long)ldC + col] = v;
                }
            }
        }
    }
}

// ---------------------------------------------------------------------------
// MI=4 GEMM kernel — 256x128 tile, m97-proven TWO-BARRIER single-buffer
// protocol: stage-all -> barrier -> compute -> barrier. Used for L1 only.
// ---------------------------------------------------------------------------
template <int ACT>
__global__ __launch_bounds__(256, 2) void gemm_bt4(
    const __hip_bfloat16* __restrict__ A, const __hip_bfloat16* __restrict__ Bt,
    const float* __restrict__ bias,
    float* __restrict__ Cf, __hip_bfloat16* __restrict__ Cb,
    int lda, int Nout, int ldC, int K)
{
    __shared__ uint4 As[1024];   // 256 rows x 4 chunks
    __shared__ uint4 Bs[512];    // 128 rows x 4 chunks

    const ushort* Ag = (const ushort*)A;
    const ushort* Bg = (const ushort*)Bt;
    const long m0 = (long)blockIdx.y * 256;
    const long n0 = (long)blockIdx.x * 128;

    const int tid  = threadIdx.x;
    const int wave = tid >> 6;
    const int lane = tid & 63;
    const int wr = wave >> 1, wc = wave & 1;
    const int ln31 = lane & 31, blk = lane >> 5;

    f32x16 acc[4][2];
#pragma unroll
    for (int i = 0; i < 4; ++i)
#pragma unroll
        for (int j = 0; j < 2; ++j) acc[i][j] = (f32x16)(0.0f);

    for (int kt = 0; kt < K; kt += 32) {
        // stage A (4 DMA/wave) + B (2 DMA/wave)
#pragma unroll
        for (int r = 0; r < 4; ++r) {
            int s = r * 256 + tid;
            int row = s >> 2, ch = (s & 3) ^ swz(row);
            gld_lds16(Ag + (m0 + row) * (long)lda + kt + ch * 8,
                      &As[r * 256 + (wave << 6)]);
        }
#pragma unroll
        for (int r = 0; r < 2; ++r) {
            int s = r * 256 + tid;
            int row = s >> 2, ch = (s & 3) ^ swz(row);
            gld_lds16(Bg + (n0 + row) * (long)K + kt + ch * 8,
                      &Bs[r * 256 + (wave << 6)]);
        }
        __syncthreads();   // drains DMA (vmcnt(0)) before any read

        bf16x8 af[2][4], bfr[2][2];
#pragma unroll
        for (int ks = 0; ks < 2; ++ks) {
            int ch = ks * 2 + blk;
#pragma unroll
            for (int mi = 0; mi < 4; ++mi) {
                int r_ = wr * 128 + mi * 32 + ln31;
                af[ks][mi] = __builtin_bit_cast(bf16x8, As[r_ * 4 + (ch ^ swz(r_))]);
            }
#pragma unroll
            for (int ni = 0; ni < 2; ++ni) {
                int n_ = wc * 64 + ni * 32 + ln31;
                bfr[ks][ni] = __builtin_bit_cast(bf16x8, Bs[n_ * 4 + (ch ^ swz(n_))]);
            }
        }
#pragma unroll
        for (int ks = 0; ks < 2; ++ks)
#pragma unroll
            for (int mi = 0; mi < 4; ++mi)
#pragma unroll
                for (int ni = 0; ni < 2; ++ni)
                    acc[mi][ni] = __builtin_amdgcn_mfma_f32_32x32x16_bf16(
                        af[ks][mi], bfr[ks][ni], acc[mi][ni], 0, 0, 0);

        __syncthreads();   // all reads done before next stage overwrites
    }

    float bs2[2];
#pragma unroll
    for (int ni = 0; ni < 2; ++ni) {
        long col = n0 + wc * 64 + ni * 32 + ln31;
        bs2[ni] = (col < Nout && bias) ? bias[col] : 0.0f;
    }

#pragma unroll
    for (int mi = 0; mi < 4; ++mi) {
#pragma unroll
        for (int ni = 0; ni < 2; ++ni) {
            long col = n0 + wc * 64 + ni * 32 + ln31;
            if (col >= Nout) continue;
#pragma unroll
            for (int reg = 0; reg < 16; ++reg) {
                long row = m0 + wr * 128 + mi * 32 + (reg & 3) + 8 * (reg >> 2) + 4 * blk;
                float v = acc[mi][ni][reg] + bs2[ni];
                if (ACT == 1) {
                    v = fmaxf(v, 0.0f);
                    Cb[row * (long)ldC + col] = __float2bfloat16(v);
                } else if (ACT == 2) {
                    v = 1.0f / (1.0f + __expf(-v));
                    Cf[row * (long)ldC + col] = v;
                } else {
                    Cf[row * (long)ldC + col] = v;
                }
            }
        }
    }
}

template <int ACT>
__global__ __launch_bounds__(256, 2) void gemm_bt2(
    const __hip_bfloat16* __restrict__ A, const __hip_bfloat16* __restrict__ Bt,
    const float* __restrict__ bias,
    float* __restrict__ Cf, __hip_bfloat16* __restrict__ Cb,
    int lda, int Nout, int ldC, int K)
{
    __shared__ uint4 As[2][512];
    __shared__ uint4 Bs[2][512];
    gemm_body2<ACT>((const ushort*)A, (const ushort*)Bt, bias, Cf, Cb,
                    lda, Nout, ldC, K,
                    (long)blockIdx.y * 128, (long)blockIdx.x * 128, As, Bs);
}

// Fused: blocks x<8 do p2 GEMM (relu bf16), block x==8 does sel-L2 (sigmoid f32).
__global__ __launch_bounds__(256, 2) void gemm_fused23(
    const __hip_bfloat16* __restrict__ act1,   // B x 2048 (sel | policy)
    const __hip_bfloat16* __restrict__ p2t, const float* __restrict__ pb2,
    __hip_bfloat16* __restrict__ actB,
    const __hip_bfloat16* __restrict__ w2t, const float* __restrict__ sel_b2,
    float* __restrict__ outP)
{
    __shared__ uint4 As[2][512];
    __shared__ uint4 Bs[2][512];
    long m0 = (long)blockIdx.y * 128;
    if (blockIdx.x < 8) {
        gemm_body2<1>((const ushort*)(act1 + 1024), (const ushort*)p2t, pb2,
                      nullptr, actB, 2048, 1024, 1024, 1024,
                      m0, (long)blockIdx.x * 128, As, Bs);
    } else {
        gemm_body2<2>((const ushort*)act1, (const ushort*)w2t, sel_b2,
                      outP, nullptr, 2048, 64, 64, 1024,
                      m0, 0, As, Bs);
    }
}

// ---------------------------------------------------------------------------
// Prep: batched transpose-cast (6 weights) + rmean + bias concat + x-cast
// ---------------------------------------------------------------------------
struct PrepArgs {
    const float* src[6];
    __hip_bfloat16* dst[6];
    int Nsrc[6];
    int Npad[6];
    const float* ranges; float* rmean;
    const float* b1; const float* b2; float* bcat;
    const float* x; __hip_bfloat16* xbf;
};

__global__ void prep_kernel(PrepArgs a)
{
    int z = blockIdx.z;
    int tx = threadIdx.x, ty = threadIdx.y;   // 32 x 8
    int t = ty * 32 + tx;
    if (z == 7) {
        int bid = blockIdx.y * 32 + blockIdx.x;   // 0..1023
        const float4* s4 = (const float4*)a.x;
        for (int i = bid * 256 + t; i < B_DIM * D_DIM / 4; i += 1024 * 256) {
            float4 v = s4[i];
            __hip_bfloat16* d = a.xbf + (size_t)i * 4;
            d[0] = __float2bfloat16(v.x);
            d[1] = __float2bfloat16(v.y);
            d[2] = __float2bfloat16(v.z);
            d[3] = __float2bfloat16(v.w);
        }
        return;
    }
    if (z == 6) {
        if (blockIdx.x || blockIdx.y) return;
        for (int j = t; j < NUM * C_DIM; j += 256) {
            float s = 0.0f;
#pragma unroll
            for (int k = 0; k < K_RANGES; ++k) s += a.ranges[j * K_RANGES + k];
            a.rmean[j] = s * (1.0f / K_RANGES);
        }
        for (int j = t; j < 1024; j += 256) {
            a.bcat[j]        = a.b1[j];
            a.bcat[1024 + j] = a.b2[j];
        }
        return;
    }
    const int Nsrc = a.Nsrc[z], Npad = a.Npad[z];
    int n0 = blockIdx.x * 32, k0 = blockIdx.y * 32;
    if (n0 >= Npad) return;
    const float* src = a.src[z];
    __hip_bfloat16* dst = a.dst[z];
    __shared__ float tile[32][33];
#pragma unroll
    for (int i = 0; i < 32; i += 8) {
        int k = k0 + ty + i, n = n0 + tx;
        tile[ty + i][tx] = (n < Nsrc) ? src[(size_t)k * Nsrc + n] : 0.0f;
    }
    __syncthreads();
#pragma unroll
    for (int i = 0; i < 32; i += 8) {
        int n = n0 + ty + i, k = k0 + tx;
        dst[(size_t)n * D_DIM + k] = __float2bfloat16(tile[tx][ty + i]);
    }
}

// ---------------------------------------------------------------------------
// Finalize: one thread per (b, n)
// ---------------------------------------------------------------------------
__global__ void finalize_kernel(
    const float* __restrict__ x, const float* __restrict__ truth,
    const float* __restrict__ ua, const float* __restrict__ ub,
    const float* __restrict__ gum, const float* __restrict__ rmean,
    const float* __restrict__ P, const float* __restrict__ W,
    float* __restrict__ out_truth, float* __restrict__ out_xcf)
{
    int idx = blockIdx.x * 256 + threadIdx.x;
    if (idx >= B_DIM * N_DIM) return;
    int b = idx >> 6, n = idx & 63;

    float tx = truth[idx];
    out_truth[idx] = tx;

    float p  = P[idx];
    float ea = -1.0f / logf(ua[idx]);
    float eb = -1.0f / logf(ub[idx]);
    float no = p * ea;
    float probs = no / (no + (1.0f - p) * eb);

    const float* Wrow = W + (size_t)idx * 16;
    const float* grow = gum + (size_t)idx * 16;
    float lo[16], g[16], xv[16];
#pragma unroll
    for (int c = 0; c < 16; c += 4) {
        float4 v = *(const float4*)(Wrow + c);
        lo[c] = v.x; lo[c + 1] = v.y; lo[c + 2] = v.z; lo[c + 3] = v.w;
        float4 gv = *(const float4*)(grow + c);
        g[c] = gv.x; g[c + 1] = gv.y; g[c + 2] = gv.z; g[c + 3] = gv.w;
    }

    bool needx = (n < NCAUSAL) || (n >= NUM);
    if (needx) {
        const float* xrow = x + (size_t)idx * 16;
#pragma unroll
        for (int c = 0; c < 16; c += 4) {
            float4 v = *(const float4*)(xrow + c);
            xv[c] = v.x; xv[c + 1] = v.y; xv[c + 2] = v.z; xv[c + 3] = v.w;
        }
    }

    if (n < NCAUSAL) {
        int curr = 0; float best = xv[0];
#pragma unroll
        for (int c = 1; c < 16; ++c)
            if (xv[c] > best) { best = xv[c]; curr = c; }
#pragma unroll
        for (int c = 0; c < 16; ++c) lo[c] += (c < curr) ? -100.0f : 1.0f;
    }

    float mx = lo[0];
#pragma unroll
    for (int c = 1; c < 16; ++c) mx = fmaxf(mx, lo[c]);
    float s = 0.0f, pr[16];
#pragma unroll
    for (int c = 0; c < 16; ++c) { pr[c] = __expf(lo[c] - mx); s += pr[c]; }
    float inv = 1.0f / s;
#pragma unroll
    for (int c = 0; c < 16; ++c)
        pr[c] = (1.0f - SMOOTH) * pr[c] * inv + (SMOOTH / C_DIM);

    float t[16];
    float mx2 = -1e30f;
#pragma unroll
    for (int c = 0; c < 16; ++c) {
        t[c] = (__logf(pr[c]) + g[c]) * (1.0f / TAU);
        mx2 = fmaxf(mx2, t[c]);
    }
    float s2 = 0.0f;
#pragma unroll
    for (int c = 0; c < 16; ++c) { t[c] = __expf(t[c] - mx2); s2 += t[c]; }
    float inv2 = 1.0f / s2;

    if (n < NUM) {
        float xt = 0.0f;
#pragma unroll
        for (int c = 0; c < 16; ++c) xt += t[c] * inv2 * rmean[n * 16 + c];
        out_xcf[(size_t)b * 544 + n] = probs * xt + (1.0f - probs) * tx;
    } else {
        float* o = out_xcf + (size_t)b * 544 + 32 + (size_t)(n - NUM) * 16;
#pragma unroll
        for (int c = 0; c < 16; ++c)
            o[c] = probs * t[c] * inv2 + (1.0f - probs) * xv[c];
    }
}

// ---------------------------------------------------------------------------
extern "C" void kernel_launch(void* const* d_in, const int* in_sizes, int n_in,
                              void* d_out, int out_size, void* d_ws, size_t ws_size,
                              hipStream_t stream)
{
    const float* x      = (const float*)d_in[0];
    const float* truth  = (const float*)d_in[1];
    const float* sel_w1 = (const float*)d_in[2];
    const float* sel_b1 = (const float*)d_in[3];
    const float* sel_w2 = (const float*)d_in[4];
    const float* sel_b2 = (const float*)d_in[5];
    const float* pw1    = (const float*)d_in[6];
    const float* pb1    = (const float*)d_in[7];
    const float* pw2    = (const float*)d_in[8];
    const float* pb2    = (const float*)d_in[9];
    const float* pw3    = (const float*)d_in[10];
    const float* pb3    = (const float*)d_in[11];
    const float* pw4    = (const float*)d_in[12];
    const float* pb4    = (const float*)d_in[13];
    const float* ranges = (const float*)d_in[14];
    const float* ua     = (const float*)d_in[15];
    const float* ub     = (const float*)d_in[16];
    const float* gum    = (const float*)d_in[17];

    float* out       = (float*)d_out;
    float* out_truth = out;                       // B*N
    float* out_xcf   = out + 524288;              // B*544
    float* out_P     = out + 4980736;             // B*N
    float* out_W     = out + 5505024;             // B*D

    // workspace layout (16B-aligned sections)
    char* w = (char*)d_ws;
    size_t off = 0;
    __hip_bfloat16* A0   = (__hip_bfloat16*)(w + off); off += (size_t)B_DIM * D_DIM * 2;
    __hip_bfloat16* act1 = (__hip_bfloat16*)(w + off); off += (size_t)B_DIM * 2048 * 2;
    __hip_bfloat16* actB = (__hip_bfloat16*)(w + off); off += (size_t)B_DIM * HP * 2;
    __hip_bfloat16* actC = (__hip_bfloat16*)(w + off); off += (size_t)B_DIM * HP * 2;
    __hip_bfloat16* Wcat = (__hip_bfloat16*)(w + off); off += (size_t)2048 * D_DIM * 2;
    __hip_bfloat16* w2t  = (__hip_bfloat16*)(w + off); off += (size_t)128 * HS * 2;
    __hip_bfloat16* p2t  = (__hip_bfloat16*)(w + off); off += (size_t)HP * HP * 2;
    __hip_bfloat16* p3t  = (__hip_bfloat16*)(w + off); off += (size_t)HP * HP * 2;
    __hip_bfloat16* p4t  = (__hip_bfloat16*)(w + off); off += (size_t)D_DIM * HP * 2;
    float* rmean         = (float*)(w + off);          off += 512 * 4;
    float* bcat          = (float*)(w + off);          off += 2048 * 4;
    if (ws_size < off) return;

    PrepArgs pa;
    pa.src[0] = sel_w1; pa.dst[0] = Wcat;               pa.Nsrc[0] = HS;    pa.Npad[0] = 1024;
    pa.src[1] = pw1;    pa.dst[1] = Wcat + 1024 * 1024; pa.Nsrc[1] = HP;    pa.Npad[1] = 1024;
    pa.src[2] = sel_w2; pa.dst[2] = w2t;                pa.Nsrc[2] = N_DIM; pa.Npad[2] = 128;
    pa.src[3] = pw2;    pa.dst[3] = p2t;                pa.Nsrc[3] = HP;    pa.Npad[3] = 1024;
    pa.src[4] = pw3;    pa.dst[4] = p3t;                pa.Nsrc[4] = HP;    pa.Npad[4] = 1024;
    pa.src[5] = pw4;    pa.dst[5] = p4t;                pa.Nsrc[5] = D_DIM; pa.Npad[5] = 1024;
    pa.ranges = ranges; pa.rmean = rmean;
    pa.b1 = sel_b1; pa.b2 = pb1; pa.bcat = bcat;
    pa.x = x; pa.xbf = A0;

    prep_kernel<<<dim3(32, 32, 8), dim3(32, 8), 0, stream>>>(pa);

    // Layer 1 fused (sel + policy): A0 x Wcat^T -> act1 (B x 2048), relu
    // MI=4 tile (256x128), two-barrier protocol
    gemm_bt4<1><<<dim3(16, 32), 256, 0, stream>>>(A0, Wcat, bcat, nullptr, act1,
                                                  D_DIM, 2048, 2048, D_DIM);
    // p2 GEMM + sel layer-2 (fused launch) — R2-proven MI=2 body
    gemm_fused23<<<dim3(9, 64), 256, 0, stream>>>(act1, p2t, pb2, actB, w2t, sel_b2, out_P);
    // p3
    gemm_bt2<1><<<dim3(8, 64), 256, 0, stream>>>(actB, p3t, pb3, nullptr, actC,
                                                 HP, HP, HP, HP);
    // p4 -> W
    gemm_bt2<0><<<dim3(8, 64), 256, 0, stream>>>(actC, p4t, pb4, out_W, nullptr,
                                                 HP, D_DIM, D_DIM, HP);

    finalize_kernel<<<(B_DIM * N_DIM + 255) / 256, 256, 0, stream>>>(
        x, truth, ua, ub, gum, rmean, out_P, out_W, out_truth, out_xcf);
}